// Round 1
// baseline (861.867 us; speedup 1.0000x reference)
//
#include <hip/hip_runtime.h>
#include <hip/hip_bf16.h>
#include <math.h>

#define TTOK 8192
#define DDIM 1024
#define HDIM 4096
#define NEXP 8
#define BM 128
#define BN 128
#define BK 64
#define MAXTILES 136              // ceil(16384/128) + 8 experts worth of padding
#define MAXSLOTS (MAXTILES * BM)  // 17408

typedef __bf16 bf16x8 __attribute__((ext_vector_type(8)));
typedef float f32x4 __attribute__((ext_vector_type(4)));

typedef const void __attribute__((address_space(1))) *gvp_t;
typedef void __attribute__((address_space(3))) *lvp_t;

__device__ __forceinline__ void gload16(const void *g, void *l) {
  // async global->LDS, 16B per lane; LDS dest is wave-uniform base + lane*16
  __builtin_amdgcn_global_load_lds((gvp_t)g, (lvp_t)l, 16, 0, 0);
}

// ---------------- small utility kernels ----------------

__global__ __launch_bounds__(64) void zero_meta(int *counts, int *cursors, float *probsum) {
  int i = threadIdx.x;
  if (i < NEXP) { counts[i] = 0; cursors[i] = 0; probsum[i] = 0.f; }
}

__global__ __launch_bounds__(256) void convert_x(const float *__restrict__ x,
                                                 __hip_bfloat16 *__restrict__ xb) {
  size_t i = ((size_t)blockIdx.x * 256 + threadIdx.x) * 4;
  float4 v = *(const float4 *)(x + i);
  union { __hip_bfloat16 h[4]; uint2 u; } p;
  p.h[0] = __float2bfloat16(v.x);
  p.h[1] = __float2bfloat16(v.y);
  p.h[2] = __float2bfloat16(v.z);
  p.h[3] = __float2bfloat16(v.w);
  *(uint2 *)(xb + i) = p.u;
}

// src [E][R][C] fp32 -> dst [E][C][R] bf16, 64x64 LDS tiles
__global__ __launch_bounds__(256) void transpose_cvt(const float *__restrict__ src,
                                                     __hip_bfloat16 *__restrict__ dst,
                                                     int R, int C) {
  __shared__ float tile[64][65];
  const int e = blockIdx.z;
  const int rb = blockIdx.x * 64, cb = blockIdx.y * 64;
  const size_t base = (size_t)e * R * C;
  const int lx = threadIdx.x & 63, ly = threadIdx.x >> 6;
#pragma unroll
  for (int i = 0; i < 64; i += 4)
    tile[ly + i][lx] = src[base + (size_t)(rb + ly + i) * C + cb + lx];
  __syncthreads();
#pragma unroll
  for (int i = 0; i < 64; i += 4)
    dst[base + (size_t)(cb + ly + i) * R + rb + lx] = __float2bfloat16(tile[lx][ly + i]);
}

// ---------------- router ----------------
// one wave per token; fp64 accumulation so top-2 selection matches the reference
__global__ __launch_bounds__(256) void router_k(const float *__restrict__ x,
                                                const float *__restrict__ Wg,
                                                int *__restrict__ counts,
                                                float *__restrict__ probsum,
                                                int *__restrict__ tok_e,
                                                float *__restrict__ tok_w) {
  __shared__ float sprob[NEXP];
  __shared__ int scnt[NEXP];
  if (threadIdx.x < NEXP) { sprob[threadIdx.x] = 0.f; scnt[threadIdx.x] = 0; }
  __syncthreads();

  const int wid = threadIdx.x >> 6, lane = threadIdx.x & 63;
  const int t = blockIdx.x * 4 + wid;
  const float *xr = x + (size_t)t * DDIM;
  double acc[NEXP];
#pragma unroll
  for (int e = 0; e < NEXP; ++e) acc[e] = 0.0;
  for (int j = lane; j < DDIM; j += 64) {
    double xv = (double)xr[j];
    const float *wrow = Wg + j * NEXP;
#pragma unroll
    for (int e = 0; e < NEXP; ++e) acc[e] += xv * (double)wrow[e];
  }
#pragma unroll
  for (int e = 0; e < NEXP; ++e) {
#pragma unroll
    for (int off = 32; off > 0; off >>= 1) acc[e] += __shfl_xor(acc[e], off, 64);
  }
  if (lane == 0) {
    double mx = acc[0];
    for (int e = 1; e < NEXP; ++e) mx = acc[e] > mx ? acc[e] : mx;
    double p[NEXP], s = 0.0;
    for (int e = 0; e < NEXP; ++e) { p[e] = exp(acc[e] - mx); s += p[e]; }
    for (int e = 0; e < NEXP; ++e) p[e] /= s;
    int i0 = 0;
    for (int e = 1; e < NEXP; ++e) if (p[e] > p[i0]) i0 = e;   // ties -> lowest idx
    int i1 = (i0 == 0) ? 1 : 0;
    for (int e = 0; e < NEXP; ++e) if (e != i0 && p[e] > p[i1]) i1 = e;
    tok_e[t] = i0 | (i1 << 16);
    tok_w[t] = (float)(p[i0] / (p[i0] + p[i1]));
    atomicAdd(&scnt[i0], 1);
    atomicAdd(&scnt[i1], 1);
    for (int e = 0; e < NEXP; ++e) atomicAdd(&sprob[e], (float)p[e]);
  }
  __syncthreads();
  if (threadIdx.x < NEXP) {
    atomicAdd(&counts[threadIdx.x], scnt[threadIdx.x]);
    atomicAdd(&probsum[threadIdx.x], sprob[threadIdx.x]);
  }
}

// ---------------- routing tables ----------------
__global__ __launch_bounds__(256) void offsets_k(const int *__restrict__ counts,
                                                 int *__restrict__ padoff,
                                                 int *__restrict__ tileexp,
                                                 int *__restrict__ total,
                                                 int *__restrict__ slot_tok,
                                                 float *__restrict__ slot_w) {
  __shared__ int sp[NEXP + 1];
  if (threadIdx.x == 0) {
    int off = 0, tt = 0;
    for (int e = 0; e < NEXP; ++e) {
      sp[e] = off;
      padoff[e] = off;
      int nt = (counts[e] + BM - 1) >> 7;
      for (int i = 0; i < nt; ++i) tileexp[tt + i] = e;
      tt += nt;
      off += nt << 7;
    }
    sp[NEXP] = off;
    *total = tt;
  }
  __syncthreads();
  // pad slots: token 0 (safe to read), weight 0 (contribution discarded)
  for (int e = 0; e < NEXP; ++e) {
    int s0 = sp[e] + counts[e], s1 = sp[e + 1];
    for (int s = s0 + (int)threadIdx.x; s < s1; s += 256) {
      slot_tok[s] = 0;
      slot_w[s] = 0.f;
    }
  }
}

__global__ __launch_bounds__(256) void assign_k(const int *__restrict__ tok_e,
                                                const float *__restrict__ tok_w,
                                                const int *__restrict__ padoff,
                                                int *__restrict__ cursors,
                                                int *__restrict__ slot_tok,
                                                float *__restrict__ slot_w,
                                                int *__restrict__ slot_of) {
  const int t = blockIdx.x * 256 + threadIdx.x;
  const int ee = tok_e[t];
  const int e0 = ee & 0xffff, e1 = ee >> 16;
  const float w0 = tok_w[t];
  int p0 = atomicAdd(&cursors[e0], 1);
  int s0 = padoff[e0] + p0;
  slot_tok[s0] = t; slot_w[s0] = w0; slot_of[2 * t] = s0;
  int p1 = atomicAdd(&cursors[e1], 1);
  int s1 = padoff[e1] + p1;
  slot_tok[s1] = t; slot_w[s1] = 1.0f - w0; slot_of[2 * t + 1] = s1;
}

// ---------------- grouped GEMM (m97 structure: 128x128 tile, BK=64, 4 waves) ----
// MODE 0: C[slot, H] = gelu(gather(x)[slot] @ W1t[e]^T + b1[e])   -> bf16 h
// MODE 1: C[slot, D] = h[slot] @ W2t[e]^T + b2[e]                 -> fp32 y
template <int MODE>
__global__ __launch_bounds__(256) void moe_gemm(const __hip_bfloat16 *__restrict__ A,
                                                const __hip_bfloat16 *__restrict__ Bw,
                                                const float *__restrict__ bias,
                                                void *__restrict__ Cout,
                                                const int *__restrict__ slot_token,
                                                const int *__restrict__ tile_expert,
                                                const int *__restrict__ total_tiles,
                                                int Kdim, int Ndim) {
  const int tile = blockIdx.x;
  if (tile >= *total_tiles) return;
  const int e = tile_expert[tile];
  const int nb = blockIdx.y * BN;

  __shared__ __align__(16) __bf16 lsA[BM][BK];
  __shared__ __align__(16) __bf16 lsB[BN][BK];

  const int tid = threadIdx.x;
  const int wid = tid >> 6;
  const int lane = tid & 63;
  const int srow = tid >> 3;        // 0..31 staging row within issue group
  const int scol = (tid & 7) * 8;   // staging col (elements)

  const size_t estride = (size_t)HDIM * DDIM;
  const __hip_bfloat16 *Bbase = Bw + (size_t)e * estride;
  const __hip_bfloat16 *asrc[4];
  const __hip_bfloat16 *bsrc[4];
#pragma unroll
  for (int i = 0; i < 4; ++i) {
    int r = tile * BM + i * 32 + srow;
    if constexpr (MODE == 0) {
      int tok = slot_token[r];
      asrc[i] = A + (size_t)tok * Kdim + scol;
    } else {
      asrc[i] = A + (size_t)r * Kdim + scol;
    }
    bsrc[i] = Bbase + (size_t)(nb + i * 32 + srow) * Kdim + scol;
  }
  char *lA = (char *)&lsA[0][0];
  char *lB = (char *)&lsB[0][0];

  f32x4 acc[4][4] = {};

  const int wr = (wid >> 1) * 64;
  const int wc = (wid & 1) * 64;
  const int fr = lane & 15;
  const int fk = (lane >> 4) * 8;

  const int nkt = Kdim / BK;
  for (int kt = 0; kt < nkt; ++kt) {
    __syncthreads();  // previous compute done before overwriting LDS
#pragma unroll
    for (int i = 0; i < 4; ++i) {
      gload16(asrc[i] + kt * BK, lA + i * 4096 + wid * 1024);
      gload16(bsrc[i] + kt * BK, lB + i * 4096 + wid * 1024);
    }
    __syncthreads();  // drains vmcnt(0): tiles resident
#pragma unroll
    for (int kc = 0; kc < 2; ++kc) {
      bf16x8 af[4], bf[4];
#pragma unroll
      for (int m = 0; m < 4; ++m)
        af[m] = *(const bf16x8 *)&lsA[wr + m * 16 + fr][kc * 32 + fk];
#pragma unroll
      for (int n = 0; n < 4; ++n)
        bf[n] = *(const bf16x8 *)&lsB[wc + n * 16 + fr][kc * 32 + fk];
#pragma unroll
      for (int m = 0; m < 4; ++m)
#pragma unroll
        for (int n = 0; n < 4; ++n)
          acc[m][n] = __builtin_amdgcn_mfma_f32_16x16x32_bf16(af[m], bf[n], acc[m][n], 0, 0, 0);
    }
  }

  // epilogue: C/D layout col=lane&15, row=(lane>>4)*4+reg  [m89 verified]
  const int row_base = tile * BM + wr + (lane >> 4) * 4;
  const int col_base = nb + wc + (lane & 15);
  const float *be = bias + (size_t)e * Ndim;
#pragma unroll
  for (int n = 0; n < 4; ++n) {
    const int col = col_base + n * 16;
    const float bv = be[col];
#pragma unroll
    for (int m = 0; m < 4; ++m) {
      const int row = row_base + m * 16;
#pragma unroll
      for (int r = 0; r < 4; ++r) {
        float v = acc[m][n][r] + bv;
        if constexpr (MODE == 0) {
          float g = 0.5f * v * (1.0f + erff(v * 0.70710678118654752f));
          ((__hip_bfloat16 *)Cout)[(size_t)(row + r) * Ndim + col] = __float2bfloat16(g);
        } else {
          ((float *)Cout)[(size_t)(row + r) * Ndim + col] = v;
        }
      }
    }
  }
}

// ---------------- combine + aux ----------------
__global__ __launch_bounds__(256) void combine_k(const float *__restrict__ yw,
                                                 const int *__restrict__ slot_of,
                                                 const float *__restrict__ slot_w,
                                                 float *__restrict__ out) {
  const int t = blockIdx.x;
  const int s0 = slot_of[2 * t], s1 = slot_of[2 * t + 1];
  const float w0 = slot_w[s0], w1 = slot_w[s1];
  const float4 *y0 = (const float4 *)(yw + (size_t)s0 * DDIM);
  const float4 *y1 = (const float4 *)(yw + (size_t)s1 * DDIM);
  float4 *o = (float4 *)(out + (size_t)t * DDIM);
  const int c = threadIdx.x;  // 256 float4 = 1024 floats
  float4 a = y0[c], b = y1[c], r;
  r.x = w0 * a.x + w1 * b.x;
  r.y = w0 * a.y + w1 * b.y;
  r.z = w0 * a.z + w1 * b.z;
  r.w = w0 * a.w + w1 * b.w;
  o[c] = r;
}

__global__ __launch_bounds__(64) void aux_k(const int *__restrict__ counts,
                                            const float *__restrict__ probsum,
                                            float *__restrict__ outp) {
  if (threadIdx.x == 0) {
    double s = 0.0;
    for (int e = 0; e < NEXP; ++e)
      s += ((double)counts[e] / (double)TTOK) * ((double)probsum[e] / (double)TTOK);
    *outp = (float)((double)NEXP * s);
  }
}

// ---------------- launch ----------------
extern "C" void kernel_launch(void *const *d_in, const int *in_sizes, int n_in,
                              void *d_out, int out_size, void *d_ws, size_t ws_size,
                              hipStream_t stream) {
  const float *x  = (const float *)d_in[0];
  const float *Wg = (const float *)d_in[1];
  const float *W1 = (const float *)d_in[2];
  const float *b1 = (const float *)d_in[3];
  const float *W2 = (const float *)d_in[4];
  const float *b2 = (const float *)d_in[5];
  float *out = (float *)d_out;

  char *ws = (char *)d_ws;
  // meta region (< 1 MiB)
  int   *counts   = (int *)(ws + 0);
  int   *cursors  = (int *)(ws + 64);
  int   *padoff   = (int *)(ws + 128);
  int   *tileexp  = (int *)(ws + 192);     // 136 ints
  int   *total    = (int *)(ws + 768);
  float *probsum  = (float *)(ws + 832);
  int   *tok_e    = (int *)(ws + 4096);    // T ints
  float *tok_w    = (float *)(ws + 36864); // T floats
  int   *slot_tok = (int *)(ws + 69632);   // MAXSLOTS ints
  float *slot_w   = (float *)(ws + 139264);// MAXSLOTS floats
  int   *slot_of  = (int *)(ws + 208896);  // 2T ints
  // data regions
  __hip_bfloat16 *xb  = (__hip_bfloat16 *)(ws + (1ull << 20));    // 16 MiB
  __hip_bfloat16 *w1t = (__hip_bfloat16 *)(ws + (18ull << 20));   // 64 MiB  [E][H][D]
  __hip_bfloat16 *w2t = (__hip_bfloat16 *)(ws + 85983232ull);     // 64 MiB  [E][D][H]
  __hip_bfloat16 *hb  = (__hip_bfloat16 *)(ws + 153092096ull);    // 136 MiB [MAXSLOTS][H]
  float          *yw  = (float *)(ws + (1ull << 20));             // reuses xb/w1t (dead by then)

  zero_meta<<<1, 64, 0, stream>>>(counts, cursors, probsum);
  convert_x<<<8192, 256, 0, stream>>>(x, xb);
  transpose_cvt<<<dim3(16, 64, 8), 256, 0, stream>>>(W1, w1t, DDIM, HDIM);
  transpose_cvt<<<dim3(64, 16, 8), 256, 0, stream>>>(W2, w2t, HDIM, DDIM);
  router_k<<<TTOK / 4, 256, 0, stream>>>(x, Wg, counts, probsum, tok_e, tok_w);
  offsets_k<<<1, 256, 0, stream>>>(counts, padoff, tileexp, total, slot_tok, slot_w);
  assign_k<<<TTOK / 256, 256, 0, stream>>>(tok_e, tok_w, padoff, cursors, slot_tok, slot_w, slot_of);
  moe_gemm<0><<<dim3(MAXTILES, HDIM / BN), 256, 0, stream>>>(
      xb, w1t, b1, hb, slot_tok, tileexp, total, DDIM, HDIM);
  moe_gemm<1><<<dim3(MAXTILES, DDIM / BN), 256, 0, stream>>>(
      hb, w2t, b2, yw, slot_tok, tileexp, total, HDIM, DDIM);
  combine_k<<<TTOK, 256, 0, stream>>>(yw, slot_of, slot_w, out);
  aux_k<<<1, 64, 0, stream>>>(counts, probsum, out + (size_t)TTOK * DDIM);
}

// Round 2
// 682.444 us; speedup vs baseline: 1.2629x; 1.2629x over previous
//
#include <hip/hip_runtime.h>
#include <hip/hip_bf16.h>
#include <math.h>

#define TTOK 8192
#define DDIM 1024
#define HDIM 4096
#define NEXP 8
#define BMT 256              // M tile (slots padded per expert to 256)
#define MAXT 72              // sum ceil(c_e/256) <= 16384/256 + 8 = 72
#define MAXSLOTS (MAXT * BMT)

typedef __bf16 bf16x8 __attribute__((ext_vector_type(8)));
typedef float f32x4 __attribute__((ext_vector_type(4)));
typedef const void __attribute__((address_space(1))) *gvp_t;
typedef void __attribute__((address_space(3))) *lvp_t;

__device__ __forceinline__ void gload16(const void *g, void *l) {
  // async global->LDS: LDS dest = wave-uniform base + lane*16 (linear), 16B/lane
  __builtin_amdgcn_global_load_lds((gvp_t)g, (lvp_t)l, 16, 0, 0);
}
__device__ __forceinline__ void bar() {
  asm volatile("" ::: "memory");
  __builtin_amdgcn_s_barrier();
  asm volatile("" ::: "memory");
}
__device__ __forceinline__ void wait_lgkm0() {
  asm volatile("s_waitcnt lgkmcnt(0)" ::: "memory");
}
template <int N> __device__ __forceinline__ void wait_vm() {
  if constexpr (N == 0) asm volatile("s_waitcnt vmcnt(0)" ::: "memory");
  else if constexpr (N == 2) asm volatile("s_waitcnt vmcnt(2)" ::: "memory");
  else if constexpr (N == 4) asm volatile("s_waitcnt vmcnt(4)" ::: "memory");
  else if constexpr (N == 6) asm volatile("s_waitcnt vmcnt(6)" ::: "memory");
}

// ---------------- small utility kernels ----------------

__global__ __launch_bounds__(64) void zero_meta(int *counts, int *cursors, float *probsum) {
  int i = threadIdx.x;
  if (i < NEXP) { counts[i] = 0; cursors[i] = 0; probsum[i] = 0.f; }
}

__global__ __launch_bounds__(256) void convert_x(const float *__restrict__ x,
                                                 __hip_bfloat16 *__restrict__ xb) {
  size_t i = ((size_t)blockIdx.x * 256 + threadIdx.x) * 4;
  float4 v = *(const float4 *)(x + i);
  union { __hip_bfloat16 h[4]; uint2 u; } p;
  p.h[0] = __float2bfloat16(v.x);
  p.h[1] = __float2bfloat16(v.y);
  p.h[2] = __float2bfloat16(v.z);
  p.h[3] = __float2bfloat16(v.w);
  *(uint2 *)(xb + i) = p.u;
}

// src [E][R][C] fp32 -> dst [E][C][R] bf16, 64x64 LDS tiles
__global__ __launch_bounds__(256) void transpose_cvt(const float *__restrict__ src,
                                                     __hip_bfloat16 *__restrict__ dst,
                                                     int R, int C) {
  __shared__ float tile[64][65];
  const int e = blockIdx.z;
  const int rb = blockIdx.x * 64, cb = blockIdx.y * 64;
  const size_t base = (size_t)e * R * C;
  const int lx = threadIdx.x & 63, ly = threadIdx.x >> 6;
#pragma unroll
  for (int i = 0; i < 64; i += 4)
    tile[ly + i][lx] = src[base + (size_t)(rb + ly + i) * C + cb + lx];
  __syncthreads();
#pragma unroll
  for (int i = 0; i < 64; i += 4)
    dst[base + (size_t)(cb + ly + i) * R + rb + lx] = __float2bfloat16(tile[lx][ly + i]);
}

// ---------------- router (fp64 accumulation: exact top-2 match) ----------------
__global__ __launch_bounds__(256) void router_k(const float *__restrict__ x,
                                                const float *__restrict__ Wg,
                                                int *__restrict__ counts,
                                                float *__restrict__ probsum,
                                                int *__restrict__ tok_e,
                                                float *__restrict__ tok_w) {
  __shared__ float sprob[NEXP];
  __shared__ int scnt[NEXP];
  if (threadIdx.x < NEXP) { sprob[threadIdx.x] = 0.f; scnt[threadIdx.x] = 0; }
  __syncthreads();

  const int wid = threadIdx.x >> 6, lane = threadIdx.x & 63;
  const int t = blockIdx.x * 4 + wid;
  const float *xr = x + (size_t)t * DDIM;
  double acc[NEXP];
#pragma unroll
  for (int e = 0; e < NEXP; ++e) acc[e] = 0.0;
  for (int j = lane; j < DDIM; j += 64) {
    double xv = (double)xr[j];
    const float *wrow = Wg + j * NEXP;
#pragma unroll
    for (int e = 0; e < NEXP; ++e) acc[e] += xv * (double)wrow[e];
  }
#pragma unroll
  for (int e = 0; e < NEXP; ++e) {
#pragma unroll
    for (int off = 32; off > 0; off >>= 1) acc[e] += __shfl_xor(acc[e], off, 64);
  }
  if (lane == 0) {
    double mx = acc[0];
    for (int e = 1; e < NEXP; ++e) mx = acc[e] > mx ? acc[e] : mx;
    double p[NEXP], s = 0.0;
    for (int e = 0; e < NEXP; ++e) { p[e] = exp(acc[e] - mx); s += p[e]; }
    for (int e = 0; e < NEXP; ++e) p[e] /= s;
    int i0 = 0;
    for (int e = 1; e < NEXP; ++e) if (p[e] > p[i0]) i0 = e;
    int i1 = (i0 == 0) ? 1 : 0;
    for (int e = 0; e < NEXP; ++e) if (e != i0 && p[e] > p[i1]) i1 = e;
    tok_e[t] = i0 | (i1 << 16);
    tok_w[t] = (float)(p[i0] / (p[i0] + p[i1]));
    atomicAdd(&scnt[i0], 1);
    atomicAdd(&scnt[i1], 1);
    for (int e = 0; e < NEXP; ++e) atomicAdd(&sprob[e], (float)p[e]);
  }
  __syncthreads();
  if (threadIdx.x < NEXP) {
    atomicAdd(&counts[threadIdx.x], scnt[threadIdx.x]);
    atomicAdd(&probsum[threadIdx.x], sprob[threadIdx.x]);
  }
}

// ---------------- routing tables (pad each expert to 256) ----------------
__global__ __launch_bounds__(256) void offsets_k(const int *__restrict__ counts,
                                                 int *__restrict__ padoff,
                                                 int *__restrict__ tileexp,
                                                 int *__restrict__ total,
                                                 int *__restrict__ slot_tok,
                                                 float *__restrict__ slot_w) {
  __shared__ int sp[NEXP + 1];
  if (threadIdx.x == 0) {
    int off = 0, tt = 0;
    for (int e = 0; e < NEXP; ++e) {
      sp[e] = off;
      padoff[e] = off;
      int nt = (counts[e] + BMT - 1) >> 8;
      for (int i = 0; i < nt; ++i) tileexp[tt + i] = e;
      tt += nt;
      off += nt << 8;
    }
    sp[NEXP] = off;
    *total = tt;
  }
  __syncthreads();
  for (int e = 0; e < NEXP; ++e) {
    int s0 = sp[e] + counts[e], s1 = sp[e + 1];
    for (int s = s0 + (int)threadIdx.x; s < s1; s += 256) {
      slot_tok[s] = 0;   // pad: token 0 (safe to read), weight 0
      slot_w[s] = 0.f;
    }
  }
}

__global__ __launch_bounds__(256) void assign_k(const int *__restrict__ tok_e,
                                                const float *__restrict__ tok_w,
                                                const int *__restrict__ padoff,
                                                int *__restrict__ cursors,
                                                int *__restrict__ slot_tok,
                                                float *__restrict__ slot_w,
                                                int *__restrict__ slot_of) {
  const int t = blockIdx.x * 256 + threadIdx.x;
  const int ee = tok_e[t];
  const int e0 = ee & 0xffff, e1 = ee >> 16;
  const float w0 = tok_w[t];
  int p0 = atomicAdd(&cursors[e0], 1);
  int s0 = padoff[e0] + p0;
  slot_tok[s0] = t; slot_w[s0] = w0; slot_of[2 * t] = s0;
  int p1 = atomicAdd(&cursors[e1], 1);
  int s1 = padoff[e1] + p1;
  slot_tok[s1] = t; slot_w[s1] = 1.0f - w0; slot_of[2 * t + 1] = s1;
}

// ---------------- 8-phase grouped GEMM ----------------
// BM=256, BN=128, BK=64, 8 waves (512 thr), 2 phases/K-tile, dbuf LDS 96KiB.
// T2: read/source XOR-swizzle byte^=(row&7)<<4 (LDS dest linear).
// T4: counted vmcnt(4)/(2), never 0 in steady state.
// C = act(A_gathered @ Bw[e]^T + bias[e]) stored bf16.
template <int KDIM_, int NDIM_, bool GELU_, bool GATHER_>
__global__ __launch_bounds__(512, 2) void moe_gemm8(
    const __hip_bfloat16 *__restrict__ A, const __hip_bfloat16 *__restrict__ Bw,
    const float *__restrict__ bias, __hip_bfloat16 *__restrict__ Cout,
    const int *__restrict__ slot_token, const int *__restrict__ tile_expert,
    const int *__restrict__ total_tiles) {
  constexpr int BUFSZ = 49152;  // A: 2 halves x 16KB, B: 16KB
  __shared__ __align__(16) char lds[2 * BUFSZ];

  const int tile = blockIdx.x;
  if (tile >= *total_tiles) return;
  const int e = tile_expert[tile];
  const int ncol = blockIdx.y * 128;
  const int tid = threadIdx.x, wid = tid >> 6, lane = tid & 63;

  // staging source pointers: row chunk + swizzled 16B column within the 128B row
  const int sr = lane >> 3;                  // row within wave's 8-row chunk
  const int scs = ((lane & 7) ^ sr) * 8;     // swizzled col (elements)
  const __hip_bfloat16 *ap[2][2], *bp[2];
  const __hip_bfloat16 *Bb = Bw + (size_t)e * ((size_t)NDIM_ * KDIM_);
#pragma unroll
  for (int h = 0; h < 2; ++h)
#pragma unroll
    for (int g = 0; g < 2; ++g) {
      int r = tile * 256 + h * 128 + g * 64 + wid * 8 + sr;
      int row = GATHER_ ? slot_token[r] : r;
      ap[h][g] = A + (size_t)row * KDIM_ + scs;
    }
#pragma unroll
  for (int g = 0; g < 2; ++g)
    bp[g] = Bb + (size_t)(ncol + g * 64 + wid * 8 + sr) * KDIM_ + scs;

  const int woff = wid * 1024;
  const int wr = wid >> 2, wc = wid & 3;     // 2x4 wave grid -> 128x32 per wave
  const int ln15 = lane & 15, g4 = lane >> 4, ln7 = lane & 7;
  int aoff[4], boff[2], coff[2];
#pragma unroll
  for (int m = 0; m < 4; ++m) aoff[m] = (wr * 64 + m * 16 + ln15) * 128;
#pragma unroll
  for (int n = 0; n < 2; ++n) boff[n] = 32768 + (wc * 32 + n * 16 + ln15) * 128;
#pragma unroll
  for (int kc = 0; kc < 2; ++kc) coff[kc] = ((kc * 4 + g4) ^ ln7) * 16;  // read swizzle

  f32x4 acc[8][2] = {};
  constexpr int nkt = KDIM_ / 64;

  // prologue: stage tile0 {A0, B0, A1}; wait A0,B0; leave [A1] in flight
  wait_vm<0>();  // retire pointer-setup loads so vmcnt counting is exact
#pragma unroll
  for (int g = 0; g < 2; ++g) gload16(ap[0][g], lds + g * 8192 + woff);
#pragma unroll
  for (int g = 0; g < 2; ++g) gload16(bp[g], lds + 32768 + g * 8192 + woff);
#pragma unroll
  for (int g = 0; g < 2; ++g) gload16(ap[1][g], lds + 16384 + g * 8192 + woff);
  wait_vm<2>();
  bar();

  for (int kt = 0; kt < nkt; ++kt) {
    const bool last = (kt == nkt - 1);
    const int b = kt & 1;
    char *cb = lds + b * BUFSZ;
    char *ob = lds + (b ^ 1) * BUFSZ;

    bf16x8 af[4][2], bfr[2][2];
    // ---------- phase 0: rows half 0 ----------
#pragma unroll
    for (int m = 0; m < 4; ++m)
#pragma unroll
      for (int kc = 0; kc < 2; ++kc)
        af[m][kc] = *(const bf16x8 *)(cb + aoff[m] + coff[kc]);
#pragma unroll
    for (int n = 0; n < 2; ++n)
#pragma unroll
      for (int kc = 0; kc < 2; ++kc)
        bfr[n][kc] = *(const bf16x8 *)(cb + boff[n] + coff[kc]);
    if (!last) {
#pragma unroll
      for (int g = 0; g < 2; ++g) gload16(ap[0][g] + (kt + 1) * 64, ob + g * 8192 + woff);
#pragma unroll
      for (int g = 0; g < 2; ++g) gload16(bp[g] + (kt + 1) * 64, ob + 32768 + g * 8192 + woff);
      wait_vm<4>();  // retire A1(kt) -> readable in phase 1
    } else {
      wait_vm<0>();
    }
    bar();
    wait_lgkm0();
    __builtin_amdgcn_s_setprio(1);
#pragma unroll
    for (int m = 0; m < 4; ++m)
#pragma unroll
      for (int n = 0; n < 2; ++n) {
        acc[m][n] = __builtin_amdgcn_mfma_f32_16x16x32_bf16(af[m][0], bfr[n][0], acc[m][n], 0, 0, 0);
        acc[m][n] = __builtin_amdgcn_mfma_f32_16x16x32_bf16(af[m][1], bfr[n][1], acc[m][n], 0, 0, 0);
      }
    __builtin_amdgcn_s_setprio(0);
    bar();

    // ---------- phase 1: rows half 1 ----------
#pragma unroll
    for (int m = 0; m < 4; ++m)
#pragma unroll
      for (int kc = 0; kc < 2; ++kc)
        af[m][kc] = *(const bf16x8 *)(cb + 16384 + aoff[m] + coff[kc]);
#pragma unroll
    for (int n = 0; n < 2; ++n)
#pragma unroll
      for (int kc = 0; kc < 2; ++kc)
        bfr[n][kc] = *(const bf16x8 *)(cb + boff[n] + coff[kc]);
    if (!last) {
#pragma unroll
      for (int g = 0; g < 2; ++g) gload16(ap[1][g] + (kt + 1) * 64, ob + 16384 + g * 8192 + woff);
      wait_vm<2>();  // retire A0(kt+1),B0(kt+1) -> readable next phase 0
    }
    bar();
    wait_lgkm0();
    __builtin_amdgcn_s_setprio(1);
#pragma unroll
    for (int m = 0; m < 4; ++m)
#pragma unroll
      for (int n = 0; n < 2; ++n) {
        acc[4 + m][n] = __builtin_amdgcn_mfma_f32_16x16x32_bf16(af[m][0], bfr[n][0], acc[4 + m][n], 0, 0, 0);
        acc[4 + m][n] = __builtin_amdgcn_mfma_f32_16x16x32_bf16(af[m][1], bfr[n][1], acc[4 + m][n], 0, 0, 0);
      }
    __builtin_amdgcn_s_setprio(0);
    bar();
  }

  // epilogue: C/D layout col=lane&15, row=(lane>>4)*4+reg [m89]
  const float *be = bias + (size_t)e * NDIM_;
  const int cbase = ncol + wc * 32 + ln15;
  float bv[2];
  bv[0] = be[cbase];
  bv[1] = be[cbase + 16];
#pragma unroll
  for (int mi = 0; mi < 8; ++mi) {
    const int row = tile * 256 + (mi >> 2) * 128 + wr * 64 + (mi & 3) * 16 + g4 * 4;
#pragma unroll
    for (int n = 0; n < 2; ++n) {
      const int col = cbase + n * 16;
#pragma unroll
      for (int r = 0; r < 4; ++r) {
        float v = acc[mi][n][r] + bv[n];
        if constexpr (GELU_) v = 0.5f * v * (1.0f + erff(v * 0.70710678118654752f));
        Cout[(size_t)(row + r) * NDIM_ + col] = __float2bfloat16(v);
      }
    }
  }
}

// ---------------- combine + aux ----------------
__global__ __launch_bounds__(256) void combine_k(const __hip_bfloat16 *__restrict__ yb,
                                                 const int *__restrict__ slot_of,
                                                 const float *__restrict__ slot_w,
                                                 float *__restrict__ out) {
  const int t = blockIdx.x;
  const int s0 = slot_of[2 * t], s1 = slot_of[2 * t + 1];
  const float w0 = slot_w[s0], w1 = slot_w[s1];
  const unsigned short *y = (const unsigned short *)yb;
  const int c = threadIdx.x * 4;
  ushort4 a = *(const ushort4 *)(y + (size_t)s0 * DDIM + c);
  ushort4 b = *(const ushort4 *)(y + (size_t)s1 * DDIM + c);
  float4 r;
  r.x = w0 * __uint_as_float((unsigned)a.x << 16) + w1 * __uint_as_float((unsigned)b.x << 16);
  r.y = w0 * __uint_as_float((unsigned)a.y << 16) + w1 * __uint_as_float((unsigned)b.y << 16);
  r.z = w0 * __uint_as_float((unsigned)a.z << 16) + w1 * __uint_as_float((unsigned)b.z << 16);
  r.w = w0 * __uint_as_float((unsigned)a.w << 16) + w1 * __uint_as_float((unsigned)b.w << 16);
  *(float4 *)(out + (size_t)t * DDIM + c) = r;
}

__global__ __launch_bounds__(64) void aux_k(const int *__restrict__ counts,
                                            const float *__restrict__ probsum,
                                            float *__restrict__ outp) {
  if (threadIdx.x == 0) {
    double s = 0.0;
    for (int e = 0; e < NEXP; ++e)
      s += ((double)counts[e] / (double)TTOK) * ((double)probsum[e] / (double)TTOK);
    *outp = (float)((double)NEXP * s);
  }
}

// ---------------- launch ----------------
extern "C" void kernel_launch(void *const *d_in, const int *in_sizes, int n_in,
                              void *d_out, int out_size, void *d_ws, size_t ws_size,
                              hipStream_t stream) {
  const float *x  = (const float *)d_in[0];
  const float *Wg = (const float *)d_in[1];
  const float *W1 = (const float *)d_in[2];
  const float *b1 = (const float *)d_in[3];
  const float *W2 = (const float *)d_in[4];
  const float *b2 = (const float *)d_in[5];
  float *out = (float *)d_out;

  char *ws = (char *)d_ws;
  const size_t MB = 1ull << 20;
  // meta (< 1 MiB)
  int   *counts   = (int *)(ws + 0);
  int   *cursors  = (int *)(ws + 64);
  int   *padoff   = (int *)(ws + 128);
  int   *tileexp  = (int *)(ws + 192);      // 72 ints
  int   *total    = (int *)(ws + 768);
  float *probsum  = (float *)(ws + 832);
  int   *tok_e    = (int *)(ws + 4096);     // T ints
  float *tok_w    = (float *)(ws + 36864);  // T floats
  int   *slot_tok = (int *)(ws + 69632);    // MAXSLOTS ints (72KB)
  float *slot_w   = (float *)(ws + 147456); // MAXSLOTS floats
  int   *slot_of  = (int *)(ws + 225280);   // 2T ints
  // data regions (peak 261 MiB)
  __hip_bfloat16 *xb  = (__hip_bfloat16 *)(ws + 1 * MB);    // 16 MiB  [T][D]
  __hip_bfloat16 *w1t = (__hip_bfloat16 *)(ws + 17 * MB);   // 64 MiB  [E][H][D]
  __hip_bfloat16 *hb  = (__hip_bfloat16 *)(ws + 81 * MB);   // 144 MiB [MAXSLOTS][H]
  __hip_bfloat16 *w2t = (__hip_bfloat16 *)(ws + 1 * MB);    // 64 MiB  [E][D][H] (after GEMM1; xb/w1t dead)
  __hip_bfloat16 *yb  = (__hip_bfloat16 *)(ws + 225 * MB);  // 36 MiB  [MAXSLOTS][D]

  zero_meta<<<1, 64, 0, stream>>>(counts, cursors, probsum);
  convert_x<<<8192, 256, 0, stream>>>(x, xb);
  transpose_cvt<<<dim3(16, 64, 8), 256, 0, stream>>>(W1, w1t, DDIM, HDIM);
  router_k<<<TTOK / 4, 256, 0, stream>>>(x, Wg, counts, probsum, tok_e, tok_w);
  offsets_k<<<1, 256, 0, stream>>>(counts, padoff, tileexp, total, slot_tok, slot_w);
  assign_k<<<TTOK / 256, 256, 0, stream>>>(tok_e, tok_w, padoff, cursors, slot_tok, slot_w, slot_of);
  moe_gemm8<DDIM, HDIM, true, true><<<dim3(MAXT, HDIM / 128), 512, 0, stream>>>(
      xb, w1t, b1, hb, slot_tok, tileexp, total);
  transpose_cvt<<<dim3(64, 16, 8), 256, 0, stream>>>(W2, w2t, HDIM, DDIM);
  moe_gemm8<HDIM, DDIM, false, false><<<dim3(MAXT, DDIM / 128), 512, 0, stream>>>(
      hb, w2t, b2, yb, slot_tok, tileexp, total);
  combine_k<<<TTOK, 256, 0, stream>>>(yb, slot_of, slot_w, out);
  aux_k<<<1, 64, 0, stream>>>(counts, probsum, out + (size_t)TTOK * DDIM);
}